// Round 1
// baseline (2473.176 us; speedup 1.0000x reference)
//
#include <hip/hip_runtime.h>

#define NENT   100000
#define NREL   100
#define DIM    128
#define NBASES 10
#define NEDGES 600000
#define CH     128            // edges per chunk/block in k_edge
#define TMAX   4788           // >= NEDGES/CH + NREL
#define PADE   612736         // >= NEDGES + NREL*(CH-1)

// ---------- indegree + relation histogram ----------
__global__ void k_deg_hist(const int* __restrict__ tgt, const int* __restrict__ rel,
                           int* __restrict__ indeg, int* __restrict__ counts) {
  __shared__ int h[NREL];
  int tid = threadIdx.x;
  if (tid < NREL) h[tid] = 0;
  __syncthreads();
  int i = blockIdx.x * blockDim.x + tid;
  if (i < NEDGES) {
    atomicAdd(&indeg[tgt[i]], 1);
    atomicAdd(&h[rel[i]], 1);
  }
  __syncthreads();
  if (tid < NREL && h[tid]) atomicAdd(&counts[tid], h[tid]);
}

// ---------- prefix scan over relations + chunk table ----------
__global__ void k_scan(const int* __restrict__ counts, int* __restrict__ poff,
                       int* __restrict__ chunk_rel, int* __restrict__ chunk_start,
                       int* __restrict__ chunk_valid, int* __restrict__ chunkT) {
  __shared__ int sc[128];
  int tid = threadIdx.x;
  int cnt = (tid < NREL) ? counts[tid] : 0;
  int nch = (cnt + CH - 1) / CH;
  sc[tid] = nch;
  __syncthreads();
  for (int d = 1; d < 128; d <<= 1) {
    int v = (tid >= d) ? sc[tid - d] : 0;
    __syncthreads();
    sc[tid] += v;
    __syncthreads();
  }
  int cb = sc[tid] - nch;  // exclusive prefix of chunk counts
  if (tid < NREL) {
    poff[tid] = cb * CH;
    for (int i = 0; i < nch; ++i) {
      chunk_rel[cb + i] = tid;
      chunk_start[cb + i] = (cb + i) * CH;
      int v = cnt - i * CH;
      if (v > CH) v = CH;
      chunk_valid[cb + i] = v;
    }
  }
  if (tid == 127) *chunkT = sc[127];
}

// ---------- scatter edges into relation-sorted arrays ----------
__global__ void k_scatter(const int* __restrict__ src, const int* __restrict__ tgt,
                          const int* __restrict__ rel, const int* __restrict__ poff,
                          int* __restrict__ fill, int* __restrict__ es, int* __restrict__ et) {
  int i = blockIdx.x * blockDim.x + threadIdx.x;
  if (i < NEDGES) {
    int r = rel[i];
    int pos = poff[r] + atomicAdd(&fill[r * 32], 1);  // fill padded to 128B/counter
    es[pos] = src[i];
    et[pos] = tgt[i];
  }
}

// ---------- per-relation weight matrices W_r = sum_b coef[r,b]*bases[b] ----------
__global__ void k_wmat(const float* __restrict__ bases, const float* __restrict__ coefs_l,
                       float* __restrict__ W) {
  int idx = blockIdx.x * blockDim.x + threadIdx.x;  // r*16384 + p, grid covers exactly
  int r = idx >> 14;
  int p = idx & 16383;
  float s = 0.f;
#pragma unroll
  for (int b = 0; b < NBASES; ++b)
    s += coefs_l[r * NBASES + b] * bases[b * DIM * DIM + p];
  W[idx] = s;
}

// ---------- edge kernel: msg = xs @ W_rel, atomic scatter-add into agg ----------
__launch_bounds__(512, 2)
__global__ void k_edge(const float* __restrict__ x, const float* __restrict__ W,
                       const int* __restrict__ es, const int* __restrict__ et,
                       const int* __restrict__ chunk_rel, const int* __restrict__ chunk_start,
                       const int* __restrict__ chunk_valid, const int* __restrict__ chunkT,
                       float* __restrict__ agg) {
  extern __shared__ float smem[];      // [DIM*DIM] W + [CH*DIM] xs = 128 KB
  float* Wl = smem;
  float* xsl = smem + DIM * DIM;
  int b = blockIdx.x;
  if (b >= *chunkT) return;
  int tid = threadIdx.x;
  int r = chunk_rel[b], base = chunk_start[b], nv = chunk_valid[b];
  // stage W_r (64 KB), coalesced
  {
    const float4* wg = (const float4*)(W + (size_t)r * DIM * DIM);
    float4* wl4 = (float4*)Wl;
#pragma unroll
    for (int i = 0; i < 8; ++i)
      wl4[tid + i * 512] = wg[tid + i * 512];
  }
  // gather 128 source rows (8 threads per row, 2 passes)
  {
    int q = tid & 7;
#pragma unroll
    for (int half = 0; half < 2; ++half) {
      int e = (tid >> 3) + half * 64;
      int sidx = (e < nv) ? es[base + e] : 0;
      const float4* xr = (const float4*)(x + (size_t)sidx * DIM);
      float4* xd = (float4*)(xsl + e * DIM);
#pragma unroll
      for (int i = 0; i < 4; ++i)
        xd[q + 8 * i] = xr[q + 8 * i];
    }
  }
  __syncthreads();
  const int lane = tid & 63;
  const int w = tid >> 6;        // wave 0..7
  const int c = lane & 31;       // column group: cols 4c..4c+3
  const int h = lane >> 5;
  const int s = w * 2 + h;       // edge slot 0..15
  const int e0 = s * 8;          // 8 edges per slot
  float4 acc[8];
#pragma unroll
  for (int e = 0; e < 8; ++e) acc[e] = make_float4(0.f, 0.f, 0.f, 0.f);
  for (int k = 0; k < DIM; k += 4) {
    float4 wv0 = *(const float4*)&Wl[(k + 0) * DIM + 4 * c];
    float4 wv1 = *(const float4*)&Wl[(k + 1) * DIM + 4 * c];
    float4 wv2 = *(const float4*)&Wl[(k + 2) * DIM + 4 * c];
    float4 wv3 = *(const float4*)&Wl[(k + 3) * DIM + 4 * c];
#pragma unroll
    for (int e = 0; e < 8; ++e) {
      float4 xv = *(const float4*)&xsl[(e0 + e) * DIM + k];
      acc[e].x += xv.x * wv0.x + xv.y * wv1.x + xv.z * wv2.x + xv.w * wv3.x;
      acc[e].y += xv.x * wv0.y + xv.y * wv1.y + xv.z * wv2.y + xv.w * wv3.y;
      acc[e].z += xv.x * wv0.z + xv.y * wv1.z + xv.z * wv2.z + xv.w * wv3.z;
      acc[e].w += xv.x * wv0.w + xv.y * wv1.w + xv.z * wv2.w + xv.w * wv3.w;
    }
  }
#pragma unroll
  for (int e = 0; e < 8; ++e) {
    int ee = e0 + e;
    if (ee < nv) {
      float* dst = agg + (size_t)et[base + ee] * DIM + 4 * c;
      atomicAdd(dst + 0, acc[e].x);
      atomicAdd(dst + 1, acc[e].y);
      atomicAdd(dst + 2, acc[e].z);
      atomicAdd(dst + 3, acc[e].w);
    }
  }
}

// ---------- combine: out = relu(agg*inv_deg + x@self_w + bias) ----------
__launch_bounds__(256, 2)
__global__ void k_combine(const float* __restrict__ xin, const float* __restrict__ sw,
                          const float* __restrict__ bias_l, const float* __restrict__ agg,
                          const int* __restrict__ indeg, float* __restrict__ out) {
  extern __shared__ float smem[];  // [DIM*DIM] + [32*DIM] = 80 KB
  float* Wl = smem;
  float* xsl = smem + DIM * DIM;
  int tid = threadIdx.x;
  int row0 = blockIdx.x * 32;
  {
    const float4* wg = (const float4*)sw;
    float4* wl4 = (float4*)Wl;
#pragma unroll
    for (int i = 0; i < 16; ++i)
      wl4[tid + i * 256] = wg[tid + i * 256];
    const float4* xg = (const float4*)(xin + (size_t)row0 * DIM);
    float4* xd = (float4*)xsl;
#pragma unroll
    for (int i = 0; i < 4; ++i)
      xd[tid + i * 256] = xg[tid + i * 256];
  }
  __syncthreads();
  const int lane = tid & 63;
  const int w = tid >> 6;        // 0..3
  const int c = lane & 31;
  const int h = lane >> 5;
  const int s4 = w * 2 + h;      // 0..7
  const int r0 = s4 * 4;         // 4 rows per slot
  float4 acc[4];
#pragma unroll
  for (int e = 0; e < 4; ++e) acc[e] = make_float4(0.f, 0.f, 0.f, 0.f);
  for (int k = 0; k < DIM; k += 4) {
    float4 wv0 = *(const float4*)&Wl[(k + 0) * DIM + 4 * c];
    float4 wv1 = *(const float4*)&Wl[(k + 1) * DIM + 4 * c];
    float4 wv2 = *(const float4*)&Wl[(k + 2) * DIM + 4 * c];
    float4 wv3 = *(const float4*)&Wl[(k + 3) * DIM + 4 * c];
#pragma unroll
    for (int e = 0; e < 4; ++e) {
      float4 xv = *(const float4*)&xsl[(r0 + e) * DIM + k];
      acc[e].x += xv.x * wv0.x + xv.y * wv1.x + xv.z * wv2.x + xv.w * wv3.x;
      acc[e].y += xv.x * wv0.y + xv.y * wv1.y + xv.z * wv2.y + xv.w * wv3.y;
      acc[e].z += xv.x * wv0.z + xv.y * wv1.z + xv.z * wv2.z + xv.w * wv3.z;
      acc[e].w += xv.x * wv0.w + xv.y * wv1.w + xv.z * wv2.w + xv.w * wv3.w;
    }
  }
#pragma unroll
  for (int e = 0; e < 4; ++e) {
    int row = row0 + r0 + e;
    int dg = indeg[row];
    float inv = 1.0f / (float)(dg > 1 ? dg : 1);
    const float4 a = *(const float4*)&agg[(size_t)row * DIM + 4 * c];
    const float4 bi = *(const float4*)&bias_l[4 * c];
    float4 o;
    o.x = fmaxf(a.x * inv + acc[e].x + bi.x, 0.f);
    o.y = fmaxf(a.y * inv + acc[e].y + bi.y, 0.f);
    o.z = fmaxf(a.z * inv + acc[e].z + bi.z, 0.f);
    o.w = fmaxf(a.w * inv + acc[e].w + bi.w, 0.f);
    *(float4*)&out[(size_t)row * DIM + 4 * c] = o;
  }
}

extern "C" void kernel_launch(void* const* d_in, const int* in_sizes, int n_in,
                              void* d_out, int out_size, void* d_ws, size_t ws_size,
                              hipStream_t stream) {
  const float* x0    = (const float*)d_in[0];
  const float* bases = (const float*)d_in[1];
  const float* coefs = (const float*)d_in[2];   // (2,100,10)
  const float* selfw = (const float*)d_in[3];   // (2,128,128)
  const float* bias  = (const float*)d_in[4];   // (2,128)
  const int* src = (const int*)d_in[5];
  const int* tgt = (const int*)d_in[6];
  const int* rel = (const int*)d_in[7];
  float* out = (float*)d_out;

  char* ws = (char*)d_ws;
  size_t off = 0;
  auto alloc = [&](size_t bytes) -> void* {
    void* p = ws + off;
    off = (off + bytes + 255) & ~(size_t)255;
    return p;
  };
  float* W  = (float*)alloc((size_t)NREL * DIM * DIM * sizeof(float));  // 6.55 MB
  float* x1 = (float*)alloc((size_t)NENT * DIM * sizeof(float));        // 51.2 MB
  int* es    = (int*)alloc((size_t)PADE * sizeof(int));
  int* et    = (int*)alloc((size_t)PADE * sizeof(int));
  int* indeg = (int*)alloc((size_t)NENT * sizeof(int));
  int* counts = (int*)alloc(NREL * sizeof(int));
  int* fill   = (int*)alloc(NREL * 32 * sizeof(int));
  int* poff   = (int*)alloc(NREL * sizeof(int));
  int* chunk_rel   = (int*)alloc(TMAX * sizeof(int));
  int* chunk_start = (int*)alloc(TMAX * sizeof(int));
  int* chunk_valid = (int*)alloc(TMAX * sizeof(int));
  int* chunkT      = (int*)alloc(sizeof(int));
  float* agg = out;  // reuse d_out as the aggregation scratch both layers

  hipMemsetAsync(indeg, 0, (size_t)NENT * sizeof(int), stream);
  hipMemsetAsync(counts, 0, NREL * sizeof(int), stream);
  hipMemsetAsync(fill, 0, NREL * 32 * sizeof(int), stream);

  k_deg_hist<<<(NEDGES + 255) / 256, 256, 0, stream>>>(tgt, rel, indeg, counts);
  k_scan<<<1, 128, 0, stream>>>(counts, poff, chunk_rel, chunk_start, chunk_valid, chunkT);
  k_scatter<<<(NEDGES + 255) / 256, 256, 0, stream>>>(src, tgt, rel, poff, fill, es, et);

  const float* xcur = x0;
  for (int l = 0; l < 2; ++l) {
    k_wmat<<<(NREL * DIM * DIM) / 256, 256, 0, stream>>>(bases, coefs + l * NREL * NBASES, W);
    hipMemsetAsync(agg, 0, (size_t)NENT * DIM * sizeof(float), stream);
    k_edge<<<TMAX, 512, (DIM * DIM + CH * DIM) * sizeof(float), stream>>>(
        xcur, W, es, et, chunk_rel, chunk_start, chunk_valid, chunkT, agg);
    float* xnext = (l == 0) ? x1 : out;
    k_combine<<<NENT / 32, 256, (DIM * DIM + 32 * DIM) * sizeof(float), stream>>>(
        xcur, selfw + l * DIM * DIM, bias + l * DIM, agg, indeg, xnext);
    xcur = xnext;
  }
}

// Round 2
// 1186.041 us; speedup vs baseline: 2.0852x; 2.0852x over previous
//
#include <hip/hip_runtime.h>

#define NENT   100000
#define NREL   100
#define DIM    128
#define NBASES 10
#define NEDGES 600000
#define CH     128            // edges per chunk/block in k_edgeA
#define TMAX   4788           // >= NEDGES/CH + NREL
#define PADE   612736         // >= NEDGES + NREL*(CH-1)
#define NB_ESCAN 98           // ceil(NENT/1024)

static __device__ __forceinline__ unsigned short f2bf(float f) {
  unsigned u = __float_as_uint(f);
  u = (u + 0x7fffu + ((u >> 16) & 1u)) >> 16;
  return (unsigned short)u;
}
static __device__ __forceinline__ float bf2f(unsigned short h) {
  return __uint_as_float((unsigned)h << 16);
}

// ---------- indegree + relation histogram ----------
__global__ void k_deg_hist(const int* __restrict__ tgt, const int* __restrict__ rel,
                           int* __restrict__ indeg, int* __restrict__ counts) {
  __shared__ int h[NREL];
  int tid = threadIdx.x;
  if (tid < NREL) h[tid] = 0;
  __syncthreads();
  int i = blockIdx.x * blockDim.x + tid;
  if (i < NEDGES) {
    atomicAdd(&indeg[tgt[i]], 1);
    atomicAdd(&h[rel[i]], 1);
  }
  __syncthreads();
  if (tid < NREL && h[tid]) atomicAdd(&counts[tid], h[tid]);
}

// ---------- prefix scan over relations + chunk table ----------
__global__ void k_scan(const int* __restrict__ counts, int* __restrict__ poff,
                       int* __restrict__ chunk_rel, int* __restrict__ chunk_start,
                       int* __restrict__ chunk_valid, int* __restrict__ chunkT) {
  __shared__ int sc[128];
  int tid = threadIdx.x;
  int cnt = (tid < NREL) ? counts[tid] : 0;
  int nch = (cnt + CH - 1) / CH;
  sc[tid] = nch;
  __syncthreads();
  for (int d = 1; d < 128; d <<= 1) {
    int v = (tid >= d) ? sc[tid - d] : 0;
    __syncthreads();
    sc[tid] += v;
    __syncthreads();
  }
  int cb = sc[tid] - nch;  // exclusive prefix of chunk counts
  if (tid < NREL) {
    poff[tid] = cb * CH;
    for (int i = 0; i < nch; ++i) {
      chunk_rel[cb + i] = tid;
      chunk_start[cb + i] = (cb + i) * CH;
      int v = cnt - i * CH;
      if (v > CH) v = CH;
      chunk_valid[cb + i] = v;
    }
  }
  if (tid == 127) *chunkT = sc[127];
}

// ---------- entity-level exclusive scan of indegree (CSR row_ptr) ----------
__global__ void k_escanA(const int* __restrict__ indeg, int* __restrict__ loc,
                         int* __restrict__ bsum) {
  __shared__ int s[256];
  int tid = threadIdx.x;
  int base = blockIdx.x * 1024 + tid * 4;
  int v0 = (base + 0 < NENT) ? indeg[base + 0] : 0;
  int v1 = (base + 1 < NENT) ? indeg[base + 1] : 0;
  int v2 = (base + 2 < NENT) ? indeg[base + 2] : 0;
  int v3 = (base + 3 < NENT) ? indeg[base + 3] : 0;
  s[tid] = v0 + v1 + v2 + v3;
  __syncthreads();
  for (int d = 1; d < 256; d <<= 1) {
    int t = (tid >= d) ? s[tid - d] : 0;
    __syncthreads();
    s[tid] += t;
    __syncthreads();
  }
  int off = (tid > 0) ? s[tid - 1] : 0;
  if (base + 0 < NENT) loc[base + 0] = off;
  if (base + 1 < NENT) loc[base + 1] = off + v0;
  if (base + 2 < NENT) loc[base + 2] = off + v0 + v1;
  if (base + 3 < NENT) loc[base + 3] = off + v0 + v1 + v2;
  if (tid == 255) bsum[blockIdx.x] = s[255];
}

__global__ void k_escanB(int* __restrict__ bsum) {
  __shared__ int s[128];
  int tid = threadIdx.x;
  s[tid] = (tid < NB_ESCAN) ? bsum[tid] : 0;
  __syncthreads();
  for (int d = 1; d < 128; d <<= 1) {
    int t = (tid >= d) ? s[tid - d] : 0;
    __syncthreads();
    s[tid] += t;
    __syncthreads();
  }
  if (tid < NB_ESCAN) bsum[tid] = (tid > 0) ? s[tid - 1] : 0;
}

__global__ void k_escanC(const int* __restrict__ loc, const int* __restrict__ bsum,
                         int* __restrict__ row_ptr) {
  int i = blockIdx.x * blockDim.x + threadIdx.x;
  if (i < NENT) row_ptr[i] = loc[i] + bsum[i >> 10];
}

// ---------- scatter: relation-sorted source ids + target-sorted msg position ----------
__global__ void k_scatter(const int* __restrict__ src, const int* __restrict__ tgt,
                          const int* __restrict__ rel, const int* __restrict__ poff,
                          const int* __restrict__ row_ptr,
                          int* __restrict__ fill_r, int* __restrict__ fill_t,
                          int* __restrict__ es, int* __restrict__ tp) {
  int i = blockIdx.x * blockDim.x + threadIdx.x;
  if (i < NEDGES) {
    int r = rel[i];
    int prel = poff[r] + atomicAdd(&fill_r[r * 32], 1);
    es[prel] = src[i];
    int t = tgt[i];
    tp[prel] = row_ptr[t] + atomicAdd(&fill_t[t], 1);
  }
}

// ---------- per-relation weight matrices W_r = sum_b coef[r,b]*bases[b] ----------
__global__ void k_wmat(const float* __restrict__ bases, const float* __restrict__ coefs_l,
                       float* __restrict__ W) {
  int idx = blockIdx.x * blockDim.x + threadIdx.x;
  int r = idx >> 14;
  int p = idx & 16383;
  float s = 0.f;
#pragma unroll
  for (int b = 0; b < NBASES; ++b)
    s += coefs_l[r * NBASES + b] * bases[b * DIM * DIM + p];
  W[idx] = s;
}

// ---------- edge kernel: msg = xs @ W_rel, streamed to target-sorted slot (bf16) ----------
__launch_bounds__(512, 2)
__global__ void k_edgeA(const float* __restrict__ x, const float* __restrict__ W,
                        const int* __restrict__ es, const int* __restrict__ tp,
                        const int* __restrict__ chunk_rel, const int* __restrict__ chunk_start,
                        const int* __restrict__ chunk_valid, const int* __restrict__ chunkT,
                        unsigned short* __restrict__ msg) {
  extern __shared__ float smem[];      // [DIM*DIM] W + [CH*DIM] xs = 128 KB
  float* Wl = smem;
  float* xsl = smem + DIM * DIM;
  int b = blockIdx.x;
  if (b >= *chunkT) return;
  int tid = threadIdx.x;
  int r = chunk_rel[b], base = chunk_start[b], nv = chunk_valid[b];
  {
    const float4* wg = (const float4*)(W + (size_t)r * DIM * DIM);
    float4* wl4 = (float4*)Wl;
#pragma unroll
    for (int i = 0; i < 8; ++i)
      wl4[tid + i * 512] = wg[tid + i * 512];
  }
  {
    int q = tid & 7;
#pragma unroll
    for (int half = 0; half < 2; ++half) {
      int e = (tid >> 3) + half * 64;
      int sidx = (e < nv) ? es[base + e] : 0;
      const float4* xr = (const float4*)(x + (size_t)sidx * DIM);
      float4* xd = (float4*)(xsl + e * DIM);
#pragma unroll
      for (int i = 0; i < 4; ++i)
        xd[q + 8 * i] = xr[q + 8 * i];
    }
  }
  __syncthreads();
  const int lane = tid & 63;
  const int w = tid >> 6;
  const int c = lane & 31;
  const int h = lane >> 5;
  const int s = w * 2 + h;
  const int e0 = s * 8;
  float4 acc[8];
#pragma unroll
  for (int e = 0; e < 8; ++e) acc[e] = make_float4(0.f, 0.f, 0.f, 0.f);
  for (int k = 0; k < DIM; k += 4) {
    float4 wv0 = *(const float4*)&Wl[(k + 0) * DIM + 4 * c];
    float4 wv1 = *(const float4*)&Wl[(k + 1) * DIM + 4 * c];
    float4 wv2 = *(const float4*)&Wl[(k + 2) * DIM + 4 * c];
    float4 wv3 = *(const float4*)&Wl[(k + 3) * DIM + 4 * c];
#pragma unroll
    for (int e = 0; e < 8; ++e) {
      float4 xv = *(const float4*)&xsl[(e0 + e) * DIM + k];
      acc[e].x += xv.x * wv0.x + xv.y * wv1.x + xv.z * wv2.x + xv.w * wv3.x;
      acc[e].y += xv.x * wv0.y + xv.y * wv1.y + xv.z * wv2.y + xv.w * wv3.y;
      acc[e].z += xv.x * wv0.z + xv.y * wv1.z + xv.z * wv2.z + xv.w * wv3.z;
      acc[e].w += xv.x * wv0.w + xv.y * wv1.w + xv.z * wv2.w + xv.w * wv3.w;
    }
  }
#pragma unroll
  for (int e = 0; e < 8; ++e) {
    int ee = e0 + e;
    if (ee < nv) {
      int p = tp[base + ee];
      ushort4 o;
      o.x = f2bf(acc[e].x);
      o.y = f2bf(acc[e].y);
      o.z = f2bf(acc[e].z);
      o.w = f2bf(acc[e].w);
      *(ushort4*)(msg + (size_t)p * DIM + 4 * c) = o;
    }
  }
}

// ---------- combine: out = relu(seg_sum(msg)*inv_deg + x@self_w + bias) ----------
__launch_bounds__(256, 2)
__global__ void k_combineB(const float* __restrict__ xin, const float* __restrict__ sw,
                           const float* __restrict__ bias_l,
                           const unsigned short* __restrict__ msg,
                           const int* __restrict__ row_ptr, const int* __restrict__ indeg,
                           float* __restrict__ out) {
  extern __shared__ float smem[];  // [DIM*DIM] + [32*DIM] = 80 KB
  float* Wl = smem;
  float* xsl = smem + DIM * DIM;
  int tid = threadIdx.x;
  int row0 = blockIdx.x * 32;
  {
    const float4* wg = (const float4*)sw;
    float4* wl4 = (float4*)Wl;
#pragma unroll
    for (int i = 0; i < 16; ++i)
      wl4[tid + i * 256] = wg[tid + i * 256];
    const float4* xg = (const float4*)(xin + (size_t)row0 * DIM);
    float4* xd = (float4*)xsl;
#pragma unroll
    for (int i = 0; i < 4; ++i)
      xd[tid + i * 256] = xg[tid + i * 256];
  }
  __syncthreads();
  const int lane = tid & 63;
  const int w = tid >> 6;
  const int c = lane & 31;
  const int h = lane >> 5;
  const int s4 = w * 2 + h;
  const int r0 = s4 * 4;
  float4 acc[4];
#pragma unroll
  for (int e = 0; e < 4; ++e) acc[e] = make_float4(0.f, 0.f, 0.f, 0.f);
  for (int k = 0; k < DIM; k += 4) {
    float4 wv0 = *(const float4*)&Wl[(k + 0) * DIM + 4 * c];
    float4 wv1 = *(const float4*)&Wl[(k + 1) * DIM + 4 * c];
    float4 wv2 = *(const float4*)&Wl[(k + 2) * DIM + 4 * c];
    float4 wv3 = *(const float4*)&Wl[(k + 3) * DIM + 4 * c];
#pragma unroll
    for (int e = 0; e < 4; ++e) {
      float4 xv = *(const float4*)&xsl[(r0 + e) * DIM + k];
      acc[e].x += xv.x * wv0.x + xv.y * wv1.x + xv.z * wv2.x + xv.w * wv3.x;
      acc[e].y += xv.x * wv0.y + xv.y * wv1.y + xv.z * wv2.y + xv.w * wv3.y;
      acc[e].z += xv.x * wv0.z + xv.y * wv1.z + xv.z * wv2.z + xv.w * wv3.z;
      acc[e].w += xv.x * wv0.w + xv.y * wv1.w + xv.z * wv2.w + xv.w * wv3.w;
    }
  }
#pragma unroll
  for (int e = 0; e < 4; ++e) {
    int row = row0 + r0 + e;
    int eb = row_ptr[row];
    int dg = indeg[row];
    float inv = 1.0f / (float)(dg > 1 ? dg : 1);
    float4 m = make_float4(0.f, 0.f, 0.f, 0.f);
    for (int j = 0; j < dg; ++j) {
      ushort4 mv = *(const ushort4*)(msg + (size_t)(eb + j) * DIM + 4 * c);
      m.x += bf2f(mv.x);
      m.y += bf2f(mv.y);
      m.z += bf2f(mv.z);
      m.w += bf2f(mv.w);
    }
    const float4 bi = *(const float4*)&bias_l[4 * c];
    float4 o;
    o.x = fmaxf(m.x * inv + acc[e].x + bi.x, 0.f);
    o.y = fmaxf(m.y * inv + acc[e].y + bi.y, 0.f);
    o.z = fmaxf(m.z * inv + acc[e].z + bi.z, 0.f);
    o.w = fmaxf(m.w * inv + acc[e].w + bi.w, 0.f);
    *(float4*)&out[(size_t)row * DIM + 4 * c] = o;
  }
}

extern "C" void kernel_launch(void* const* d_in, const int* in_sizes, int n_in,
                              void* d_out, int out_size, void* d_ws, size_t ws_size,
                              hipStream_t stream) {
  const float* x0    = (const float*)d_in[0];
  const float* bases = (const float*)d_in[1];
  const float* coefs = (const float*)d_in[2];
  const float* selfw = (const float*)d_in[3];
  const float* bias  = (const float*)d_in[4];
  const int* src = (const int*)d_in[5];
  const int* tgt = (const int*)d_in[6];
  const int* rel = (const int*)d_in[7];
  float* out = (float*)d_out;

  char* ws = (char*)d_ws;
  size_t off = 0;
  auto alloc = [&](size_t bytes) -> void* {
    void* p = ws + off;
    off = (off + bytes + 255) & ~(size_t)255;
    return p;
  };
  float* W   = (float*)alloc((size_t)NREL * DIM * DIM * sizeof(float));   // 6.55 MB
  unsigned short* msg = (unsigned short*)alloc((size_t)NEDGES * DIM * 2); // 153.6 MB
  int* es    = (int*)alloc((size_t)PADE * sizeof(int));
  int* tp    = (int*)alloc((size_t)PADE * sizeof(int));
  int* indeg = (int*)alloc((size_t)NENT * sizeof(int));
  int* row_ptr = (int*)alloc((size_t)NENT * sizeof(int));
  int* loc     = (int*)alloc((size_t)NENT * sizeof(int));
  int* fill_t  = (int*)alloc((size_t)NENT * sizeof(int));
  int* bsum    = (int*)alloc(128 * sizeof(int));
  int* counts  = (int*)alloc(NREL * sizeof(int));
  int* fill_r  = (int*)alloc(NREL * 32 * sizeof(int));
  int* poff    = (int*)alloc(NREL * sizeof(int));
  int* chunk_rel   = (int*)alloc(TMAX * sizeof(int));
  int* chunk_start = (int*)alloc(TMAX * sizeof(int));
  int* chunk_valid = (int*)alloc(TMAX * sizeof(int));
  int* chunkT      = (int*)alloc(sizeof(int));

  hipMemsetAsync(indeg, 0, (size_t)NENT * sizeof(int), stream);
  hipMemsetAsync(fill_t, 0, (size_t)NENT * sizeof(int), stream);
  hipMemsetAsync(counts, 0, NREL * sizeof(int), stream);
  hipMemsetAsync(fill_r, 0, NREL * 32 * sizeof(int), stream);

  k_deg_hist<<<(NEDGES + 255) / 256, 256, 0, stream>>>(tgt, rel, indeg, counts);
  k_scan<<<1, 128, 0, stream>>>(counts, poff, chunk_rel, chunk_start, chunk_valid, chunkT);
  k_escanA<<<NB_ESCAN, 256, 0, stream>>>(indeg, loc, bsum);
  k_escanB<<<1, 128, 0, stream>>>(bsum);
  k_escanC<<<(NENT + 255) / 256, 256, 0, stream>>>(loc, bsum, row_ptr);
  k_scatter<<<(NEDGES + 255) / 256, 256, 0, stream>>>(src, tgt, rel, poff, row_ptr,
                                                      fill_r, fill_t, es, tp);

  const float* xcur = x0;
  for (int l = 0; l < 2; ++l) {
    k_wmat<<<(NREL * DIM * DIM) / 256, 256, 0, stream>>>(bases, coefs + l * NREL * NBASES, W);
    k_edgeA<<<TMAX, 512, (DIM * DIM + CH * DIM) * sizeof(float), stream>>>(
        xcur, W, es, tp, chunk_rel, chunk_start, chunk_valid, chunkT, msg);
    k_combineB<<<NENT / 32, 256, (DIM * DIM + 32 * DIM) * sizeof(float), stream>>>(
        xcur, selfw + l * DIM * DIM, bias + l * DIM, msg, row_ptr, indeg, out);
    xcur = out;
  }
}

// Round 3
// 497.078 us; speedup vs baseline: 4.9754x; 2.3860x over previous
//
#include <hip/hip_runtime.h>

#define NENT    100000
#define NENTPAD 100096      // 782*128, padded for combine staging
#define NREL    100
#define DIM     128
#define NBASES  10
#define NEDGES  600000
#define CH      128
#define TMAX    4788
#define PADE    612736
#define NB_ESCAN 98

typedef unsigned short u16;
typedef unsigned int   u32;
typedef __bf16  bf16x8 __attribute__((ext_vector_type(8)));
typedef float   f32x16 __attribute__((ext_vector_type(16)));

static __device__ __forceinline__ u16 f2bf(float f) {
  u32 u = __float_as_uint(f);
  u = (u + 0x7fffu + ((u >> 16) & 1u)) >> 16;
  return (u16)u;
}
static __device__ __forceinline__ float bf2f(u32 h) {
  return __uint_as_float(h << 16);
}
static __device__ __forceinline__ u32 pk2(float a, float b) {
  return (u32)f2bf(a) | ((u32)f2bf(b) << 16);
}
#define GLD16(g, l) __builtin_amdgcn_global_load_lds( \
    (__attribute__((address_space(1))) u32*)(g), \
    (__attribute__((address_space(3))) u32*)(l), 16, 0, 0)

// ---------- indegree + relation histogram ----------
__global__ void k_deg_hist(const int* __restrict__ tgt, const int* __restrict__ rel,
                           int* __restrict__ indeg, int* __restrict__ counts) {
  __shared__ int h[NREL];
  int tid = threadIdx.x;
  if (tid < NREL) h[tid] = 0;
  __syncthreads();
  int i = blockIdx.x * blockDim.x + tid;
  if (i < NEDGES) {
    atomicAdd(&indeg[tgt[i]], 1);
    atomicAdd(&h[rel[i]], 1);
  }
  __syncthreads();
  if (tid < NREL && h[tid]) atomicAdd(&counts[tid], h[tid]);
}

// ---------- prefix scan over relations + chunk table ----------
__global__ void k_scan(const int* __restrict__ counts, int* __restrict__ poff,
                       int* __restrict__ chunk_rel, int* __restrict__ chunk_start,
                       int* __restrict__ chunk_valid, int* __restrict__ chunkT) {
  __shared__ int sc[128];
  int tid = threadIdx.x;
  int cnt = (tid < NREL) ? counts[tid] : 0;
  int nch = (cnt + CH - 1) / CH;
  sc[tid] = nch;
  __syncthreads();
  for (int d = 1; d < 128; d <<= 1) {
    int v = (tid >= d) ? sc[tid - d] : 0;
    __syncthreads();
    sc[tid] += v;
    __syncthreads();
  }
  int cb = sc[tid] - nch;
  if (tid < NREL) {
    poff[tid] = cb * CH;
    for (int i = 0; i < nch; ++i) {
      chunk_rel[cb + i] = tid;
      chunk_start[cb + i] = (cb + i) * CH;
      int v = cnt - i * CH;
      if (v > CH) v = CH;
      chunk_valid[cb + i] = v;
    }
  }
  if (tid == 127) *chunkT = sc[127];
}

// ---------- entity-level exclusive scan of indegree (CSR row_ptr) ----------
__global__ void k_escanA(const int* __restrict__ indeg, int* __restrict__ loc,
                         int* __restrict__ bsum) {
  __shared__ int s[256];
  int tid = threadIdx.x;
  int base = blockIdx.x * 1024 + tid * 4;
  int v0 = (base + 0 < NENT) ? indeg[base + 0] : 0;
  int v1 = (base + 1 < NENT) ? indeg[base + 1] : 0;
  int v2 = (base + 2 < NENT) ? indeg[base + 2] : 0;
  int v3 = (base + 3 < NENT) ? indeg[base + 3] : 0;
  s[tid] = v0 + v1 + v2 + v3;
  __syncthreads();
  for (int d = 1; d < 256; d <<= 1) {
    int t = (tid >= d) ? s[tid - d] : 0;
    __syncthreads();
    s[tid] += t;
    __syncthreads();
  }
  int off = (tid > 0) ? s[tid - 1] : 0;
  if (base + 0 < NENT) loc[base + 0] = off;
  if (base + 1 < NENT) loc[base + 1] = off + v0;
  if (base + 2 < NENT) loc[base + 2] = off + v0 + v1;
  if (base + 3 < NENT) loc[base + 3] = off + v0 + v1 + v2;
  if (tid == 255) bsum[blockIdx.x] = s[255];
}

__global__ void k_escanB(int* __restrict__ bsum) {
  __shared__ int s[128];
  int tid = threadIdx.x;
  s[tid] = (tid < NB_ESCAN) ? bsum[tid] : 0;
  __syncthreads();
  for (int d = 1; d < 128; d <<= 1) {
    int t = (tid >= d) ? s[tid - d] : 0;
    __syncthreads();
    s[tid] += t;
    __syncthreads();
  }
  if (tid < NB_ESCAN) bsum[tid] = (tid > 0) ? s[tid - 1] : 0;
}

__global__ void k_escanC(const int* __restrict__ loc, const int* __restrict__ bsum,
                         int* __restrict__ row_ptr) {
  int i = blockIdx.x * blockDim.x + threadIdx.x;
  if (i < NENT) row_ptr[i] = loc[i] + bsum[i >> 10];
}

// ---------- scatter: relation-sorted source ids + target-sorted msg position ----------
__global__ void k_scatter(const int* __restrict__ src, const int* __restrict__ tgt,
                          const int* __restrict__ rel, const int* __restrict__ poff,
                          const int* __restrict__ row_ptr,
                          int* __restrict__ fill_r, int* __restrict__ fill_t,
                          int* __restrict__ es, int* __restrict__ tp) {
  int i = blockIdx.x * blockDim.x + threadIdx.x;
  if (i < NEDGES) {
    int r = rel[i];
    int prel = poff[r] + atomicAdd(&fill_r[r * 32], 1);
    es[prel] = src[i];
    int t = tgt[i];
    tp[prel] = row_ptr[t] + atomicAdd(&fill_t[t], 1);
  }
}

// ---------- x fp32 -> bf16, pre-swizzled rows (chunk g holds logical chunk g^(row&7)) ----------
__global__ void k_tobf(const float* __restrict__ x, u16* __restrict__ xbf) {
  int t = blockIdx.x * 256 + threadIdx.x;   // row*16 + g
  int row = t >> 4, g = t & 15;
  int c = g ^ (row & 7);
  const float4* xr = (const float4*)(x + (size_t)row * DIM + c * 8);
  float4 a = xr[0], b = xr[1];
  uint4 o;
  o.x = pk2(a.x, a.y); o.y = pk2(a.z, a.w);
  o.z = pk2(b.x, b.y); o.w = pk2(b.z, b.w);
  *(uint4*)(xbf + (size_t)row * DIM + g * 8) = o;
}

// ---------- Wt[r][dim][k] = sum_b coef*bases[b][k][dim], bf16, pre-swizzled ----------
__global__ void k_wmatT(const float* __restrict__ bases, const float* __restrict__ coefs_l,
                        u16* __restrict__ Wt) {
  int g = blockIdx.x * 256 + threadIdx.x;   // r*2048 + k8*128 + dim
  int r = g >> 11;
  int rem = g & 2047;
  int k8 = rem >> 7;
  int dim = rem & 127;
  float cf[NBASES];
#pragma unroll
  for (int bb = 0; bb < NBASES; ++bb) cf[bb] = coefs_l[r * NBASES + bb];
  float v[8];
#pragma unroll
  for (int i = 0; i < 8; ++i) v[i] = 0.f;
  for (int bb = 0; bb < NBASES; ++bb) {
    const float* bp = bases + (size_t)bb * DIM * DIM + (k8 * 8) * DIM + dim;
#pragma unroll
    for (int i = 0; i < 8; ++i) v[i] += cf[bb] * bp[i * DIM];
  }
  uint4 o;
  o.x = pk2(v[0], v[1]); o.y = pk2(v[2], v[3]);
  o.z = pk2(v[4], v[5]); o.w = pk2(v[6], v[7]);
  *(uint4*)(Wt + (size_t)r * DIM * DIM + dim * DIM + ((k8 ^ (dim & 7)) * 8)) = o;
}

// ---------- self_w transposed bf16 swizzled (both layers) ----------
__global__ void k_swtT(const float* __restrict__ sw, u16* __restrict__ swt) {
  int g = blockIdx.x * 256 + threadIdx.x;   // l*2048 + k8*128 + dim
  int ll = g >> 11;
  int rem = g & 2047;
  int k8 = rem >> 7;
  int dim = rem & 127;
  const float* bp = sw + (size_t)ll * DIM * DIM + (k8 * 8) * DIM + dim;
  float v[8];
#pragma unroll
  for (int i = 0; i < 8; ++i) v[i] = bp[i * DIM];
  uint4 o;
  o.x = pk2(v[0], v[1]); o.y = pk2(v[2], v[3]);
  o.z = pk2(v[4], v[5]); o.w = pk2(v[6], v[7]);
  *(uint4*)(swt + (size_t)ll * DIM * DIM + dim * DIM + ((k8 ^ (dim & 7)) * 8)) = o;
}

// ---------- edge kernel: msg^T = Wt * xs^T via MFMA ----------
__launch_bounds__(512, 4)
__global__ void k_edgeM(const u16* __restrict__ xbf, const u16* __restrict__ Wt,
                        const int* __restrict__ es, const int* __restrict__ tp,
                        const int* __restrict__ chunk_rel, const int* __restrict__ chunk_start,
                        const int* __restrict__ chunk_valid, const int* __restrict__ chunkT,
                        u16* __restrict__ msg) {
  __shared__ __align__(16) char smem[65536];   // [0,32K): Wt  [32K,64K): xs
  int b = blockIdx.x;
  if (b >= *chunkT) return;
  int tid = threadIdx.x;
  int r = chunk_rel[b], base = chunk_start[b], nv = chunk_valid[b];
  {
    const char* wg = (const char*)(Wt + (size_t)r * DIM * DIM);
#pragma unroll
    for (int it = 0; it < 4; ++it) {
      int off = it * 8192 + tid * 16;
      GLD16(wg + off, smem + off);
    }
  }
  {
    int e = tid >> 2, q = tid & 3;
    int sidx = (e < nv) ? es[base + e] : 0;
    const char* xr = (const char*)(xbf + (size_t)sidx * DIM);
    char* xd = smem + 32768 + e * 256;
    int xk = (sidx & 7) ^ (e & 7);
#pragma unroll
    for (int i = 0; i < 4; ++i) {
      int g = q * 4 + i;
      uint4 v = *(const uint4*)(xr + g * 16);
      *(uint4*)(xd + ((g ^ xk) * 16)) = v;
    }
  }
  __syncthreads();
  int w = tid >> 6, l = tid & 63;
  int lr = l & 31, hi = l >> 5;
  int dt = w & 3;
  int d = dt * 32 + lr;
  int e1 = (w >> 2) * 32 + lr;
  const char* wb = smem;
  const char* xb = smem + 32768;
  f32x16 accA, accB;
#pragma unroll
  for (int i = 0; i < 16; ++i) { accA[i] = 0.f; accB[i] = 0.f; }
  int aswz = d & 7, bswz = lr & 7;
#pragma unroll
  for (int s = 0; s < 8; ++s) {
    int c = s * 2 + hi;
    bf16x8 av = *(const bf16x8*)(wb + d * 256 + ((c ^ aswz) * 16));
    bf16x8 b1 = *(const bf16x8*)(xb + e1 * 256 + ((c ^ bswz) * 16));
    bf16x8 b2 = *(const bf16x8*)(xb + (e1 + 64) * 256 + ((c ^ bswz) * 16));
    accA = __builtin_amdgcn_mfma_f32_32x32x16_bf16(av, b1, accA, 0, 0, 0);
    accB = __builtin_amdgcn_mfma_f32_32x32x16_bf16(av, b2, accB, 0, 0, 0);
  }
#pragma unroll
  for (int t = 0; t < 2; ++t) {
    int e = e1 + t * 64;
    if (e < nv) {
      int p = tp[base + e];
      u16* mrow = msg + (size_t)p * DIM + dt * 32 + hi * 4;
#pragma unroll
      for (int q = 0; q < 4; ++q) {
        float v0 = t ? accB[4 * q + 0] : accA[4 * q + 0];
        float v1 = t ? accB[4 * q + 1] : accA[4 * q + 1];
        float v2 = t ? accB[4 * q + 2] : accA[4 * q + 2];
        float v3 = t ? accB[4 * q + 3] : accA[4 * q + 3];
        uint2 o;
        o.x = pk2(v0, v1); o.y = pk2(v2, v3);
        *(uint2*)(mrow + 8 * q) = o;
      }
    }
  }
}

// ---------- combine: relu(segsum(msg)*inv + x@self_w + bias) via MFMA ----------
__launch_bounds__(512, 4)
__global__ void k_combM(const u16* __restrict__ xbf, const u16* __restrict__ swt,
                        const float* __restrict__ bias_l, const u16* __restrict__ msg,
                        const int* __restrict__ row_ptr, const int* __restrict__ indeg,
                        float* __restrict__ outf, u16* __restrict__ outb, int last) {
  __shared__ __align__(16) char smem[65536];
  int tid = threadIdx.x;
  int r0 = blockIdx.x * 128;
  {
    const char* wg = (const char*)swt;
    const char* xg = (const char*)(xbf + (size_t)r0 * DIM);
#pragma unroll
    for (int it = 0; it < 4; ++it) {
      int off = it * 8192 + tid * 16;
      GLD16(wg + off, smem + off);
      GLD16(xg + off, smem + 32768 + off);
    }
  }
  __syncthreads();
  int w = tid >> 6, l = tid & 63;
  int lr = l & 31, hi = l >> 5;
  int dt = w & 3;
  int d = dt * 32 + lr;
  int e1 = (w >> 2) * 32 + lr;
  const char* wb = smem;
  const char* xb = smem + 32768;
  f32x16 accA, accB;
#pragma unroll
  for (int i = 0; i < 16; ++i) { accA[i] = 0.f; accB[i] = 0.f; }
  int aswz = d & 7, bswz = lr & 7;
#pragma unroll
  for (int s = 0; s < 8; ++s) {
    int c = s * 2 + hi;
    bf16x8 av = *(const bf16x8*)(wb + d * 256 + ((c ^ aswz) * 16));
    bf16x8 b1 = *(const bf16x8*)(xb + e1 * 256 + ((c ^ bswz) * 16));
    bf16x8 b2 = *(const bf16x8*)(xb + (e1 + 64) * 256 + ((c ^ bswz) * 16));
    accA = __builtin_amdgcn_mfma_f32_32x32x16_bf16(av, b1, accA, 0, 0, 0);
    accB = __builtin_amdgcn_mfma_f32_32x32x16_bf16(av, b2, accB, 0, 0, 0);
  }
#pragma unroll
  for (int t = 0; t < 2; ++t) {
    int ent = r0 + e1 + t * 64;
    int vald = (ent < NENT);
    int eb = vald ? row_ptr[ent] : 0;
    int dg = vald ? indeg[ent] : 0;
    float inv = 1.f / (float)(dg > 1 ? dg : 1);
    float ms[16];
#pragma unroll
    for (int i = 0; i < 16; ++i) ms[i] = 0.f;
    const u16* mp = msg + (size_t)eb * DIM + dt * 32 + hi * 4;
    for (int j = 0; j < dg; ++j) {
#pragma unroll
      for (int q = 0; q < 4; ++q) {
        uint2 m = *(const uint2*)(mp + 8 * q);
        ms[4 * q + 0] += bf2f(m.x & 0xffffu);
        ms[4 * q + 1] += bf2f(m.x >> 16);
        ms[4 * q + 2] += bf2f(m.y & 0xffffu);
        ms[4 * q + 3] += bf2f(m.y >> 16);
      }
      mp += DIM;
    }
    if (vald) {
#pragma unroll
      for (int q = 0; q < 4; ++q) {
        float4 bi = *(const float4*)(bias_l + dt * 32 + hi * 4 + 8 * q);
        float a0 = t ? accB[4 * q + 0] : accA[4 * q + 0];
        float a1 = t ? accB[4 * q + 1] : accA[4 * q + 1];
        float a2 = t ? accB[4 * q + 2] : accA[4 * q + 2];
        float a3 = t ? accB[4 * q + 3] : accA[4 * q + 3];
        float o0 = fmaxf(ms[4 * q + 0] * inv + a0 + bi.x, 0.f);
        float o1 = fmaxf(ms[4 * q + 1] * inv + a1 + bi.y, 0.f);
        float o2 = fmaxf(ms[4 * q + 2] * inv + a2 + bi.z, 0.f);
        float o3 = fmaxf(ms[4 * q + 3] * inv + a3 + bi.w, 0.f);
        if (last) {
          float4 o = make_float4(o0, o1, o2, o3);
          *(float4*)(outf + (size_t)ent * DIM + dt * 32 + hi * 4 + 8 * q) = o;
        } else {
          int c16 = 4 * dt + q;
          uint2 o;
          o.x = pk2(o0, o1); o.y = pk2(o2, o3);
          *(uint2*)(outb + (size_t)ent * DIM + ((c16 ^ (ent & 7)) * 8) + 4 * hi) = o;
        }
      }
    }
  }
}

extern "C" void kernel_launch(void* const* d_in, const int* in_sizes, int n_in,
                              void* d_out, int out_size, void* d_ws, size_t ws_size,
                              hipStream_t stream) {
  const float* x0    = (const float*)d_in[0];
  const float* bases = (const float*)d_in[1];
  const float* coefs = (const float*)d_in[2];
  const float* selfw = (const float*)d_in[3];
  const float* bias  = (const float*)d_in[4];
  const int* src = (const int*)d_in[5];
  const int* tgt = (const int*)d_in[6];
  const int* rel = (const int*)d_in[7];
  float* out = (float*)d_out;

  char* ws = (char*)d_ws;
  size_t off = 0;
  auto alloc = [&](size_t bytes) -> void* {
    void* p = ws + off;
    off = (off + bytes + 255) & ~(size_t)255;
    return p;
  };
  u16* Wt   = (u16*)alloc((size_t)NREL * DIM * DIM * 2);      // 3.3 MB
  u16* swt  = (u16*)alloc((size_t)2 * DIM * DIM * 2);         // 64 KB
  u16* xbf  = (u16*)alloc((size_t)NENTPAD * DIM * 2);         // 25.6 MB
  u16* msg  = (u16*)alloc((size_t)NEDGES * DIM * 2);          // 153.6 MB
  int* es      = (int*)alloc((size_t)PADE * sizeof(int));
  int* tp      = (int*)alloc((size_t)PADE * sizeof(int));
  int* indeg   = (int*)alloc((size_t)NENT * sizeof(int));
  int* row_ptr = (int*)alloc((size_t)NENT * sizeof(int));
  int* loc     = (int*)alloc((size_t)NENT * sizeof(int));
  int* fill_t  = (int*)alloc((size_t)NENT * sizeof(int));
  int* bsum    = (int*)alloc(128 * sizeof(int));
  int* counts  = (int*)alloc(NREL * sizeof(int));
  int* fill_r  = (int*)alloc(NREL * 32 * sizeof(int));
  int* poff    = (int*)alloc(NREL * sizeof(int));
  int* chunk_rel   = (int*)alloc(TMAX * sizeof(int));
  int* chunk_start = (int*)alloc(TMAX * sizeof(int));
  int* chunk_valid = (int*)alloc(TMAX * sizeof(int));
  int* chunkT      = (int*)alloc(sizeof(int));

  hipMemsetAsync(indeg, 0, (size_t)NENT * sizeof(int), stream);
  hipMemsetAsync(fill_t, 0, (size_t)NENT * sizeof(int), stream);
  hipMemsetAsync(counts, 0, NREL * sizeof(int), stream);
  hipMemsetAsync(fill_r, 0, NREL * 32 * sizeof(int), stream);

  k_deg_hist<<<(NEDGES + 255) / 256, 256, 0, stream>>>(tgt, rel, indeg, counts);
  k_scan<<<1, 128, 0, stream>>>(counts, poff, chunk_rel, chunk_start, chunk_valid, chunkT);
  k_escanA<<<NB_ESCAN, 256, 0, stream>>>(indeg, loc, bsum);
  k_escanB<<<1, 128, 0, stream>>>(bsum);
  k_escanC<<<(NENT + 255) / 256, 256, 0, stream>>>(loc, bsum, row_ptr);
  k_scatter<<<(NEDGES + 255) / 256, 256, 0, stream>>>(src, tgt, rel, poff, row_ptr,
                                                      fill_r, fill_t, es, tp);
  k_tobf<<<(NENT * 16) / 256, 256, 0, stream>>>(x0, xbf);
  k_swtT<<<16, 256, 0, stream>>>(selfw, swt);

  for (int l = 0; l < 2; ++l) {
    k_wmatT<<<(NREL * 2048) / 256, 256, 0, stream>>>(bases, coefs + l * NREL * NBASES, Wt);
    k_edgeM<<<TMAX, 512, 0, stream>>>(xbf, Wt, es, tp,
                                      chunk_rel, chunk_start, chunk_valid, chunkT, msg);
    k_combM<<<NENTPAD / 128, 512, 0, stream>>>(xbf, swt + (size_t)l * DIM * DIM,
                                               bias + l * DIM, msg, row_ptr, indeg,
                                               out, xbf, l == 0 ? 0 : 1);
  }
}

// Round 4
// 398.339 us; speedup vs baseline: 6.2087x; 1.2479x over previous
//
#include <hip/hip_runtime.h>

#define NENT    100000
#define NENTPAD 100096      // 782*128, padded for combine staging
#define NREL    100
#define DIM     128
#define NBASES  10
#define NEDGES  600000
#define CH      128
#define TMAX    4788
#define PADE    612736
#define NB_ESCAN 98
#define EPB     4096        // edges per sort block
#define NBH     147         // ceil(NEDGES/EPB)

typedef unsigned short u16;
typedef unsigned int   u32;
typedef __bf16  bf16x8 __attribute__((ext_vector_type(8)));
typedef float   f32x16 __attribute__((ext_vector_type(16)));

static __device__ __forceinline__ u16 f2bf(float f) {
  u32 u = __float_as_uint(f);
  u = (u + 0x7fffu + ((u >> 16) & 1u)) >> 16;
  return (u16)u;
}
static __device__ __forceinline__ float bf2f(u32 h) {
  return __uint_as_float(h << 16);
}
static __device__ __forceinline__ u32 pk2(float a, float b) {
  return (u32)f2bf(a) | ((u32)f2bf(b) << 16);
}
#define GLD16(g, l) __builtin_amdgcn_global_load_lds( \
    (__attribute__((address_space(1))) u32*)(g), \
    (__attribute__((address_space(3))) u32*)(l), 16, 0, 0)

// ---------- phase 1: per-block relation histogram + indegree ----------
__global__ __launch_bounds__(1024) void k_hist2(const int* __restrict__ tgt,
                                                const int* __restrict__ rel,
                                                int* __restrict__ indeg,
                                                int* __restrict__ hist) {
  __shared__ int h[NREL];
  int tid = threadIdx.x, blk = blockIdx.x;
  if (tid < NREL) h[tid] = 0;
  __syncthreads();
  int base = blk * EPB;
  int nv = NEDGES - base; if (nv > EPB) nv = EPB;
#pragma unroll
  for (int k = 0; k < 4; ++k) {
    int j = tid + k * 1024;
    if (j < nv) {
      int i = base + j;
      atomicAdd(&indeg[tgt[i]], 1);
      atomicAdd(&h[rel[i]], 1);
    }
  }
  __syncthreads();
  if (tid < NREL) hist[tid * NBH + blk] = h[tid];
}

// ---------- phase 2: chunk table + absolute per-(rel,block) offsets ----------
__global__ __launch_bounds__(1024) void k_scan2(int* __restrict__ hist,
                                                int* __restrict__ chunk_rel,
                                                int* __restrict__ chunk_start,
                                                int* __restrict__ chunk_valid,
                                                int* __restrict__ chunkT) {
  __shared__ int sh[NREL * NBH];   // 57.4 KB
  __shared__ int cnt[NREL];
  __shared__ int cb[128];
  int tid = threadIdx.x;
  for (int i = tid; i < NREL * NBH; i += 1024) sh[i] = hist[i];
  __syncthreads();
  if (tid < NREL) {
    int s = 0;
    for (int b = 0; b < NBH; ++b) s += sh[tid * NBH + b];
    cnt[tid] = s;
  }
  __syncthreads();
  if (tid < 128) cb[tid] = (tid < NREL) ? (cnt[tid] + CH - 1) / CH : 0;
  __syncthreads();
  for (int d = 1; d < 128; d <<= 1) {
    int t = 0;
    if (tid < 128 && tid >= d) t = cb[tid - d];
    __syncthreads();
    if (tid < 128) cb[tid] += t;
    __syncthreads();
  }
  if (tid < NREL) {
    int c = cnt[tid];
    int nch = (c + CH - 1) / CH;
    int cb0 = cb[tid] - nch;
    int poff = cb0 * CH;
    for (int i = 0; i < nch; ++i) {
      chunk_rel[cb0 + i] = tid;
      chunk_start[cb0 + i] = (cb0 + i) * CH;
      int v = c - i * CH;
      if (v > CH) v = CH;
      chunk_valid[cb0 + i] = v;
    }
    // exclusive scan of this relation's per-block counts, based at poff
    int run = poff;
    for (int b = 0; b < NBH; ++b) {
      int t = sh[tid * NBH + b];
      sh[tid * NBH + b] = run;
      run += t;
    }
  }
  if (tid == 127) *chunkT = cb[127];
  __syncthreads();
  for (int i = tid; i < NREL * NBH; i += 1024) hist[i] = sh[i];
}

// ---------- phase 3: staged, relation-grouped scatter (coalesced writes) ----------
__global__ __launch_bounds__(1024) void k_scatter2(const int* __restrict__ src,
                                                   const int* __restrict__ tgt,
                                                   const int* __restrict__ rel,
                                                   const int* __restrict__ hist,
                                                   const int* __restrict__ row_ptr,
                                                   int* __restrict__ fill_t,
                                                   int* __restrict__ es,
                                                   int* __restrict__ tp) {
  __shared__ int lh[NREL];      // local counts
  __shared__ int lc[NREL];      // running rank counters
  __shared__ int goff[NREL];    // absolute base for this block
  __shared__ int ls[128];       // inclusive scan of lh
  __shared__ int es_l[EPB];
  __shared__ int tp_l[EPB];
  __shared__ int dst_l[EPB];
  int tid = threadIdx.x, blk = blockIdx.x;
  int base = blk * EPB;
  int nv = NEDGES - base; if (nv > EPB) nv = EPB;
  if (tid < NREL) {
    lh[tid] = 0; lc[tid] = 0;
    goff[tid] = hist[tid * NBH + blk];
  }
  __syncthreads();
  int r4[4], s4[4], t4[4];
#pragma unroll
  for (int k = 0; k < 4; ++k) {
    int j = tid + k * 1024;
    if (j < nv) {
      int i = base + j;
      r4[k] = rel[i]; s4[k] = src[i]; t4[k] = tgt[i];
      atomicAdd(&lh[r4[k]], 1);
    } else r4[k] = -1;
  }
  __syncthreads();
  if (tid < 128) ls[tid] = (tid < NREL) ? lh[tid] : 0;
  __syncthreads();
  for (int d = 1; d < 128; d <<= 1) {
    int t = 0;
    if (tid < 128 && tid >= d) t = ls[tid - d];
    __syncthreads();
    if (tid < 128) ls[tid] += t;
    __syncthreads();
  }
#pragma unroll
  for (int k = 0; k < 4; ++k) {
    if (r4[k] >= 0) {
      int r = r4[k];
      int rank = atomicAdd(&lc[r], 1);
      int lpos = ls[r] - lh[r] + rank;
      es_l[lpos] = s4[k];
      dst_l[lpos] = goff[r] + rank;
      tp_l[lpos] = row_ptr[t4[k]] + atomicAdd(&fill_t[t4[k]], 1);
    }
  }
  __syncthreads();
  for (int j = tid; j < nv; j += 1024) {
    int d = dst_l[j];
    es[d] = es_l[j];
    tp[d] = tp_l[j];
  }
}

// ---------- entity-level exclusive scan of indegree (CSR row_ptr) ----------
__global__ void k_escanA(const int* __restrict__ indeg, int* __restrict__ loc,
                         int* __restrict__ bsum) {
  __shared__ int s[256];
  int tid = threadIdx.x;
  int base = blockIdx.x * 1024 + tid * 4;
  int v0 = (base + 0 < NENT) ? indeg[base + 0] : 0;
  int v1 = (base + 1 < NENT) ? indeg[base + 1] : 0;
  int v2 = (base + 2 < NENT) ? indeg[base + 2] : 0;
  int v3 = (base + 3 < NENT) ? indeg[base + 3] : 0;
  s[tid] = v0 + v1 + v2 + v3;
  __syncthreads();
  for (int d = 1; d < 256; d <<= 1) {
    int t = (tid >= d) ? s[tid - d] : 0;
    __syncthreads();
    s[tid] += t;
    __syncthreads();
  }
  int off = (tid > 0) ? s[tid - 1] : 0;
  if (base + 0 < NENT) loc[base + 0] = off;
  if (base + 1 < NENT) loc[base + 1] = off + v0;
  if (base + 2 < NENT) loc[base + 2] = off + v0 + v1;
  if (base + 3 < NENT) loc[base + 3] = off + v0 + v1 + v2;
  if (tid == 255) bsum[blockIdx.x] = s[255];
}

__global__ void k_escanB(int* __restrict__ bsum) {
  __shared__ int s[128];
  int tid = threadIdx.x;
  s[tid] = (tid < NB_ESCAN) ? bsum[tid] : 0;
  __syncthreads();
  for (int d = 1; d < 128; d <<= 1) {
    int t = (tid >= d) ? s[tid - d] : 0;
    __syncthreads();
    s[tid] += t;
    __syncthreads();
  }
  if (tid < NB_ESCAN) bsum[tid] = (tid > 0) ? s[tid - 1] : 0;
}

__global__ void k_escanC(const int* __restrict__ loc, const int* __restrict__ bsum,
                         int* __restrict__ row_ptr) {
  int i = blockIdx.x * blockDim.x + threadIdx.x;
  if (i < NENT) row_ptr[i] = loc[i] + bsum[i >> 10];
}

// ---------- x fp32 -> bf16, pre-swizzled rows ----------
__global__ void k_tobf(const float* __restrict__ x, u16* __restrict__ xbf) {
  int t = blockIdx.x * 256 + threadIdx.x;   // row*16 + g
  int row = t >> 4, g = t & 15;
  int c = g ^ (row & 7);
  const float4* xr = (const float4*)(x + (size_t)row * DIM + c * 8);
  float4 a = xr[0], b = xr[1];
  uint4 o;
  o.x = pk2(a.x, a.y); o.y = pk2(a.z, a.w);
  o.z = pk2(b.x, b.y); o.w = pk2(b.z, b.w);
  *(uint4*)(xbf + (size_t)row * DIM + g * 8) = o;
}

// ---------- Wt[r][dim][k] = sum_b coef*bases[b][k][dim], bf16, pre-swizzled ----------
__global__ void k_wmatT(const float* __restrict__ bases, const float* __restrict__ coefs_l,
                        u16* __restrict__ Wt) {
  int g = blockIdx.x * 256 + threadIdx.x;   // r*2048 + k8*128 + dim
  int r = g >> 11;
  int rem = g & 2047;
  int k8 = rem >> 7;
  int dim = rem & 127;
  float cf[NBASES];
#pragma unroll
  for (int bb = 0; bb < NBASES; ++bb) cf[bb] = coefs_l[r * NBASES + bb];
  float v[8];
#pragma unroll
  for (int i = 0; i < 8; ++i) v[i] = 0.f;
  for (int bb = 0; bb < NBASES; ++bb) {
    const float* bp = bases + (size_t)bb * DIM * DIM + (k8 * 8) * DIM + dim;
#pragma unroll
    for (int i = 0; i < 8; ++i) v[i] += cf[bb] * bp[i * DIM];
  }
  uint4 o;
  o.x = pk2(v[0], v[1]); o.y = pk2(v[2], v[3]);
  o.z = pk2(v[4], v[5]); o.w = pk2(v[6], v[7]);
  *(uint4*)(Wt + (size_t)r * DIM * DIM + dim * DIM + ((k8 ^ (dim & 7)) * 8)) = o;
}

// ---------- self_w transposed bf16 swizzled (both layers) ----------
__global__ void k_swtT(const float* __restrict__ sw, u16* __restrict__ swt) {
  int g = blockIdx.x * 256 + threadIdx.x;
  int ll = g >> 11;
  int rem = g & 2047;
  int k8 = rem >> 7;
  int dim = rem & 127;
  const float* bp = sw + (size_t)ll * DIM * DIM + (k8 * 8) * DIM + dim;
  float v[8];
#pragma unroll
  for (int i = 0; i < 8; ++i) v[i] = bp[i * DIM];
  uint4 o;
  o.x = pk2(v[0], v[1]); o.y = pk2(v[2], v[3]);
  o.z = pk2(v[4], v[5]); o.w = pk2(v[6], v[7]);
  *(uint4*)(swt + (size_t)ll * DIM * DIM + dim * DIM + ((k8 ^ (dim & 7)) * 8)) = o;
}

// ---------- edge kernel: msg^T = Wt * xs^T via MFMA ----------
__launch_bounds__(512, 4)
__global__ void k_edgeM(const u16* __restrict__ xbf, const u16* __restrict__ Wt,
                        const int* __restrict__ es, const int* __restrict__ tp,
                        const int* __restrict__ chunk_rel, const int* __restrict__ chunk_start,
                        const int* __restrict__ chunk_valid, const int* __restrict__ chunkT,
                        u16* __restrict__ msg) {
  __shared__ __align__(16) char smem[65536];   // [0,32K): Wt  [32K,64K): xs
  int b = blockIdx.x;
  if (b >= *chunkT) return;
  int tid = threadIdx.x;
  int r = chunk_rel[b], base = chunk_start[b], nv = chunk_valid[b];
  {
    const char* wg = (const char*)(Wt + (size_t)r * DIM * DIM);
#pragma unroll
    for (int it = 0; it < 4; ++it) {
      int off = it * 8192 + tid * 16;
      GLD16(wg + off, smem + off);
    }
  }
  {
    int e = tid >> 2, q = tid & 3;
    int sidx = (e < nv) ? es[base + e] : 0;
    const char* xr = (const char*)(xbf + (size_t)sidx * DIM);
    char* xd = smem + 32768 + e * 256;
    int xk = (sidx & 7) ^ (e & 7);
#pragma unroll
    for (int i = 0; i < 4; ++i) {
      int g = q * 4 + i;
      uint4 v = *(const uint4*)(xr + g * 16);
      *(uint4*)(xd + ((g ^ xk) * 16)) = v;
    }
  }
  __syncthreads();
  int w = tid >> 6, l = tid & 63;
  int lr = l & 31, hi = l >> 5;
  int dt = w & 3;
  int d = dt * 32 + lr;
  int e1 = (w >> 2) * 32 + lr;
  const char* wb = smem;
  const char* xb = smem + 32768;
  f32x16 accA, accB;
#pragma unroll
  for (int i = 0; i < 16; ++i) { accA[i] = 0.f; accB[i] = 0.f; }
  int aswz = d & 7, bswz = lr & 7;
#pragma unroll
  for (int s = 0; s < 8; ++s) {
    int c = s * 2 + hi;
    bf16x8 av = *(const bf16x8*)(wb + d * 256 + ((c ^ aswz) * 16));
    bf16x8 b1 = *(const bf16x8*)(xb + e1 * 256 + ((c ^ bswz) * 16));
    bf16x8 b2 = *(const bf16x8*)(xb + (e1 + 64) * 256 + ((c ^ bswz) * 16));
    accA = __builtin_amdgcn_mfma_f32_32x32x16_bf16(av, b1, accA, 0, 0, 0);
    accB = __builtin_amdgcn_mfma_f32_32x32x16_bf16(av, b2, accB, 0, 0, 0);
  }
#pragma unroll
  for (int t = 0; t < 2; ++t) {
    int e = e1 + t * 64;
    if (e < nv) {
      int p = tp[base + e];
      u16* mrow = msg + (size_t)p * DIM + dt * 32 + hi * 4;
#pragma unroll
      for (int q = 0; q < 4; ++q) {
        float v0 = t ? accB[4 * q + 0] : accA[4 * q + 0];
        float v1 = t ? accB[4 * q + 1] : accA[4 * q + 1];
        float v2 = t ? accB[4 * q + 2] : accA[4 * q + 2];
        float v3 = t ? accB[4 * q + 3] : accA[4 * q + 3];
        uint2 o;
        o.x = pk2(v0, v1); o.y = pk2(v2, v3);
        *(uint2*)(mrow + 8 * q) = o;
      }
    }
  }
}

// ---------- combine: relu(segsum(msg)*inv + x@self_w + bias) via MFMA ----------
__launch_bounds__(512, 4)
__global__ void k_combM(const u16* __restrict__ xbf, const u16* __restrict__ swt,
                        const float* __restrict__ bias_l, const u16* __restrict__ msg,
                        const int* __restrict__ row_ptr, const int* __restrict__ indeg,
                        float* __restrict__ outf, u16* __restrict__ outb, int last) {
  __shared__ __align__(16) char smem[65536];
  int tid = threadIdx.x;
  int r0 = blockIdx.x * 128;
  {
    const char* wg = (const char*)swt;
    const char* xg = (const char*)(xbf + (size_t)r0 * DIM);
#pragma unroll
    for (int it = 0; it < 4; ++it) {
      int off = it * 8192 + tid * 16;
      GLD16(wg + off, smem + off);
      GLD16(xg + off, smem + 32768 + off);
    }
  }
  __syncthreads();
  int w = tid >> 6, l = tid & 63;
  int lr = l & 31, hi = l >> 5;
  int dt = w & 3;
  int d = dt * 32 + lr;
  int e1 = (w >> 2) * 32 + lr;
  const char* wb = smem;
  const char* xb = smem + 32768;
  f32x16 accA, accB;
#pragma unroll
  for (int i = 0; i < 16; ++i) { accA[i] = 0.f; accB[i] = 0.f; }
  int aswz = d & 7, bswz = lr & 7;
#pragma unroll
  for (int s = 0; s < 8; ++s) {
    int c = s * 2 + hi;
    bf16x8 av = *(const bf16x8*)(wb + d * 256 + ((c ^ aswz) * 16));
    bf16x8 b1 = *(const bf16x8*)(xb + e1 * 256 + ((c ^ bswz) * 16));
    bf16x8 b2 = *(const bf16x8*)(xb + (e1 + 64) * 256 + ((c ^ bswz) * 16));
    accA = __builtin_amdgcn_mfma_f32_32x32x16_bf16(av, b1, accA, 0, 0, 0);
    accB = __builtin_amdgcn_mfma_f32_32x32x16_bf16(av, b2, accB, 0, 0, 0);
  }
#pragma unroll
  for (int t = 0; t < 2; ++t) {
    int ent = r0 + e1 + t * 64;
    int vald = (ent < NENT);
    int eb = vald ? row_ptr[ent] : 0;
    int dg = vald ? indeg[ent] : 0;
    float inv = 1.f / (float)(dg > 1 ? dg : 1);
    float ms[16];
#pragma unroll
    for (int i = 0; i < 16; ++i) ms[i] = 0.f;
    const u16* mp = msg + (size_t)eb * DIM + dt * 32 + hi * 4;
    for (int j = 0; j < dg; ++j) {
#pragma unroll
      for (int q = 0; q < 4; ++q) {
        uint2 m = *(const uint2*)(mp + 8 * q);
        ms[4 * q + 0] += bf2f(m.x & 0xffffu);
        ms[4 * q + 1] += bf2f(m.x >> 16);
        ms[4 * q + 2] += bf2f(m.y & 0xffffu);
        ms[4 * q + 3] += bf2f(m.y >> 16);
      }
      mp += DIM;
    }
    if (vald) {
#pragma unroll
      for (int q = 0; q < 4; ++q) {
        float4 bi = *(const float4*)(bias_l + dt * 32 + hi * 4 + 8 * q);
        float a0 = t ? accB[4 * q + 0] : accA[4 * q + 0];
        float a1 = t ? accB[4 * q + 1] : accA[4 * q + 1];
        float a2 = t ? accB[4 * q + 2] : accA[4 * q + 2];
        float a3 = t ? accB[4 * q + 3] : accA[4 * q + 3];
        float o0 = fmaxf(ms[4 * q + 0] * inv + a0 + bi.x, 0.f);
        float o1 = fmaxf(ms[4 * q + 1] * inv + a1 + bi.y, 0.f);
        float o2 = fmaxf(ms[4 * q + 2] * inv + a2 + bi.z, 0.f);
        float o3 = fmaxf(ms[4 * q + 3] * inv + a3 + bi.w, 0.f);
        if (last) {
          float4 o = make_float4(o0, o1, o2, o3);
          *(float4*)(outf + (size_t)ent * DIM + dt * 32 + hi * 4 + 8 * q) = o;
        } else {
          int c16 = 4 * dt + q;
          uint2 o;
          o.x = pk2(o0, o1); o.y = pk2(o2, o3);
          *(uint2*)(outb + (size_t)ent * DIM + ((c16 ^ (ent & 7)) * 8) + 4 * hi) = o;
        }
      }
    }
  }
}

extern "C" void kernel_launch(void* const* d_in, const int* in_sizes, int n_in,
                              void* d_out, int out_size, void* d_ws, size_t ws_size,
                              hipStream_t stream) {
  const float* x0    = (const float*)d_in[0];
  const float* bases = (const float*)d_in[1];
  const float* coefs = (const float*)d_in[2];
  const float* selfw = (const float*)d_in[3];
  const float* bias  = (const float*)d_in[4];
  const int* src = (const int*)d_in[5];
  const int* tgt = (const int*)d_in[6];
  const int* rel = (const int*)d_in[7];
  float* out = (float*)d_out;

  char* ws = (char*)d_ws;
  size_t off = 0;
  auto alloc = [&](size_t bytes) -> void* {
    void* p = ws + off;
    off = (off + bytes + 255) & ~(size_t)255;
    return p;
  };
  u16* Wt   = (u16*)alloc((size_t)NREL * DIM * DIM * 2);      // 3.3 MB
  u16* swt  = (u16*)alloc((size_t)2 * DIM * DIM * 2);         // 64 KB
  u16* xbf  = (u16*)alloc((size_t)NENTPAD * DIM * 2);         // 25.6 MB
  u16* msg  = (u16*)alloc((size_t)NEDGES * DIM * 2);          // 153.6 MB
  int* es      = (int*)alloc((size_t)PADE * sizeof(int));
  int* tp      = (int*)alloc((size_t)PADE * sizeof(int));
  int* indeg   = (int*)alloc((size_t)NENT * sizeof(int));
  int* row_ptr = (int*)alloc((size_t)NENT * sizeof(int));
  int* loc     = (int*)alloc((size_t)NENT * sizeof(int));
  int* fill_t  = (int*)alloc((size_t)NENT * sizeof(int));
  int* bsum    = (int*)alloc(128 * sizeof(int));
  int* hist    = (int*)alloc((size_t)NREL * NBH * sizeof(int));
  int* chunk_rel   = (int*)alloc(TMAX * sizeof(int));
  int* chunk_start = (int*)alloc(TMAX * sizeof(int));
  int* chunk_valid = (int*)alloc(TMAX * sizeof(int));
  int* chunkT      = (int*)alloc(sizeof(int));

  hipMemsetAsync(indeg, 0, (size_t)NENT * sizeof(int), stream);
  hipMemsetAsync(fill_t, 0, (size_t)NENT * sizeof(int), stream);

  k_hist2<<<NBH, 1024, 0, stream>>>(tgt, rel, indeg, hist);
  k_scan2<<<1, 1024, 0, stream>>>(hist, chunk_rel, chunk_start, chunk_valid, chunkT);
  k_escanA<<<NB_ESCAN, 256, 0, stream>>>(indeg, loc, bsum);
  k_escanB<<<1, 128, 0, stream>>>(bsum);
  k_escanC<<<(NENT + 255) / 256, 256, 0, stream>>>(loc, bsum, row_ptr);
  k_scatter2<<<NBH, 1024, 0, stream>>>(src, tgt, rel, hist, row_ptr, fill_t, es, tp);
  k_tobf<<<(NENT * 16) / 256, 256, 0, stream>>>(x0, xbf);
  k_swtT<<<16, 256, 0, stream>>>(selfw, swt);

  for (int l = 0; l < 2; ++l) {
    k_wmatT<<<(NREL * 2048) / 256, 256, 0, stream>>>(bases, coefs + l * NREL * NBASES, Wt);
    k_edgeM<<<TMAX, 512, 0, stream>>>(xbf, Wt, es, tp,
                                      chunk_rel, chunk_start, chunk_valid, chunkT, msg);
    k_combM<<<NENTPAD / 128, 512, 0, stream>>>(xbf, swt + (size_t)l * DIM * DIM,
                                               bias + l * DIM, msg, row_ptr, indeg,
                                               out, xbf, l == 0 ? 0 : 1);
  }
}